// Round 4
// baseline (656.185 us; speedup 1.0000x reference)
//
#include <hip/hip_runtime.h>
#include <stdint.h>

#define B_N 2
#define S_N 2048
#define D_N 4096
#define H_N 32
#define KVH_N 8
#define HD_N 128
#define NQT (S_N / 64)
// 1/sqrt(128) * log2(e)  (Q prescale; softmax runs in exp2 domain)
#define QS_LOG2E 0.12751743f

typedef __attribute__((ext_vector_type(8))) short bf16x8;
typedef __attribute__((ext_vector_type(4))) float f32x4;

__device__ __forceinline__ unsigned short f2bf(float f) {
    union { float f; unsigned u; } v; v.f = f;
    unsigned u = v.u;
    u += 0x7fffu + ((u >> 16) & 1u);   // RNE
    return (unsigned short)(u >> 16);
}
__device__ __forceinline__ float bf2f(unsigned short h) {
    union { unsigned u; float f; } v; v.u = ((unsigned)h) << 16;
    return v.f;
}
__device__ __forceinline__ unsigned cvt_pk_bf16(float lo, float hi) {
    unsigned r;
    asm("v_cvt_pk_bf16_f32 %0, %1, %2" : "=v"(r) : "v"(lo), "v"(hi));
    return r;
}

__device__ __forceinline__ void gl16(const unsigned short* g, unsigned short* l) {
    __builtin_amdgcn_global_load_lds(
        (const __attribute__((address_space(1))) void*)g,
        (__attribute__((address_space(3))) void*)l, 16, 0, 0);
}

// ---------------- f32 -> bf16 conversion (vectorized) ----------------
__global__ void __launch_bounds__(256) conv_f32_bf16(const float* __restrict__ in,
                                                     unsigned short* __restrict__ out) {
    int i = (blockIdx.x * 256 + threadIdx.x) * 4;
    float4 v = *(const float4*)(in + i);
    ushort4 o;
    o.x = f2bf(v.x); o.y = f2bf(v.y); o.z = f2bf(v.z); o.w = f2bf(v.w);
    *(ushort4*)(out + i) = o;
}

// ---------------- RoPE (in-place on bf16, pairs are adjacent) ----------------
template<int HEADS, int STRIDE>
__global__ void __launch_bounds__(256) rope_kernel(unsigned short* __restrict__ t,
                                                   const float* __restrict__ cosb,
                                                   const float* __restrict__ sinb,
                                                   float scale) {
    int p = blockIdx.x * 256 + threadIdx.x;
    int i = p & 63;
    int hr = p >> 6;
    int m = hr / HEADS;
    int hh = hr - m * HEADS;
    int s = m & (S_N - 1);
    size_t off = (size_t)m * STRIDE + hh * HD_N + 2 * i;
    unsigned v = *(const unsigned*)(t + off);
    float t0 = bf2f((unsigned short)(v & 0xffffu));
    float t1 = bf2f((unsigned short)(v >> 16));
    float c = cosb[s * 64 + i], sn = sinb[s * 64 + i];
    float o0 = (t0 * c - t1 * sn) * scale;
    float o1 = (t0 * sn + t1 * c) * scale;
    *(unsigned*)(t + off) = (unsigned)f2bf(o0) | ((unsigned)f2bf(o1) << 16);
}

// ========================= 256x256 8-phase NT GEMM (unchanged) =========================
#define BAR() __builtin_amdgcn_s_barrier()
#define VMC4() asm volatile("s_waitcnt vmcnt(4)" ::: "memory")

template<int F32OUT>
__global__ void __launch_bounds__(512, 2)
gemm256(const unsigned short* __restrict__ A, const unsigned short* __restrict__ Bm,
        void* __restrict__ Cv, int M, int N, int K) {
    __shared__ unsigned short ldsA[2][16384];
    __shared__ unsigned short ldsB[2][16384];

    const int tid = threadIdx.x;
    const int lane = tid & 63;
    const int w = tid >> 6;
    const int li = lane & 15, lg = lane >> 4;
    const int wr = w >> 2, wc = w & 3;

    const int nwg = gridDim.x;
    const int cpx = nwg >> 3;
    const int wg = (blockIdx.x & 7) * cpx + (blockIdx.x >> 3);
    const int nbn = N >> 8;
    const int bm = wg / nbn, bn = wg - bm * nbn;
    const int m0 = bm << 8, n0 = bn << 8;

    const int rbase = ((tid >> 7) << 4) + ((tid >> 2) & 15);
    const int cstg = ((tid >> 6) & 1) * 32 + (((tid & 3) * 8) ^ (((tid >> 5) & 1) << 4));
    const unsigned short* Asrc[4];
    const unsigned short* Bsrc[4];
#pragma unroll
    for (int hj = 0; hj < 4; ++hj) {
        Asrc[hj] = A + (size_t)(m0 + hj * 64 + rbase) * K + cstg;
        Bsrc[hj] = Bm + (size_t)(n0 + hj * 64 + rbase) * K + cstg;
    }
    const int dstoff = tid * 8;
    const int kmask = K - 1;

    f32x4 acc[8][4];
#pragma unroll
    for (int i = 0; i < 8; ++i)
#pragma unroll
        for (int j = 0; j < 4; ++j) acc[i][j] = (f32x4){0.f, 0.f, 0.f, 0.f};

    const int colpart = (lg * 16) ^ ((li >> 3) << 5);

#define STG(SRC, LDSBUF, H, T) do {                                         \
        int kk_ = ((T) * 64) & kmask;                                       \
        gl16(SRC[(H)*2 + 0] + kk_, &LDSBUF[((H)*2 + 0) * 4096 + dstoff]);   \
        gl16(SRC[(H)*2 + 1] + kk_, &LDSBUF[((H)*2 + 1) * 4096 + dstoff]);   \
    } while (0)

#define LDB(buf) do {                                                        \
        _Pragma("unroll")                                                    \
        for (int ni_ = 0; ni_ < 4; ++ni_) {                                  \
            _Pragma("unroll")                                                \
            for (int ks_ = 0; ks_ < 2; ++ks_)                                \
                bfr[ni_][ks_] = *(const bf16x8*)((const char*)&ldsB[buf][0]  \
                    + (wc * 4 + ni_) * 2048 + ks_ * 1024 + li * 64 + colpart); \
        }                                                                    \
    } while (0)

#define LDA(buf, q) do {                                                     \
        _Pragma("unroll")                                                    \
        for (int m_ = 0; m_ < 2; ++m_) {                                     \
            _Pragma("unroll")                                                \
            for (int ks_ = 0; ks_ < 2; ++ks_)                                \
                af[m_][ks_] = *(const bf16x8*)((const char*)&ldsA[buf][0]    \
                    + (wr * 8 + (q) * 2 + m_) * 2048 + ks_ * 1024 + li * 64 + colpart); \
        }                                                                    \
    } while (0)

#define MFMAQ(q) do {                                                        \
        __builtin_amdgcn_s_setprio(1);                                       \
        _Pragma("unroll")                                                    \
        for (int ks_ = 0; ks_ < 2; ++ks_) {                                  \
            _Pragma("unroll")                                                \
            for (int m_ = 0; m_ < 2; ++m_) {                                 \
                _Pragma("unroll")                                            \
                for (int ni_ = 0; ni_ < 4; ++ni_)                            \
                    acc[(q)*2 + m_][ni_] = __builtin_amdgcn_mfma_f32_16x16x32_bf16( \
                        af[m_][ks_], bfr[ni_][ks_], acc[(q)*2 + m_][ni_], 0, 0, 0); \
            }                                                                \
        }                                                                    \
        __builtin_amdgcn_s_setprio(0);                                       \
    } while (0)

    STG(Asrc, ldsA[0], 0, 0); STG(Asrc, ldsA[0], 1, 0);
    STG(Bsrc, ldsB[0], 0, 0); STG(Bsrc, ldsB[0], 1, 0);
    STG(Bsrc, ldsB[1], 0, 1); STG(Bsrc, ldsB[1], 1, 1);
    VMC4();
    BAR();

    const int NIT = K >> 7;
    bf16x8 bfr[4][2], af[2][2];
#pragma unroll 1
    for (int i = 0; i < NIT; ++i) {
        const int T = 2 * i;
        LDB(0); LDA(0, 0);
        STG(Asrc, ldsA[1], 0, T + 1);
        BAR(); MFMAQ(0); BAR();
        LDA(0, 1);
        STG(Asrc, ldsA[1], 1, T + 1);
        STG(Bsrc, ldsB[0], 0, T + 2);
        BAR(); MFMAQ(1); BAR();
        LDA(0, 2);
        STG(Bsrc, ldsB[0], 1, T + 2);
        BAR(); MFMAQ(2); BAR();
        LDA(0, 3);
        BAR(); MFMAQ(3); VMC4(); BAR();
        LDB(1); LDA(1, 0);
        STG(Asrc, ldsA[0], 0, T + 2);
        BAR(); MFMAQ(0); BAR();
        LDA(1, 1);
        STG(Asrc, ldsA[0], 1, T + 2);
        BAR(); MFMAQ(1); BAR();
        LDA(1, 2);
        STG(Bsrc, ldsB[1], 0, T + 3);
        BAR(); MFMAQ(2); BAR();
        LDA(1, 3);
        STG(Bsrc, ldsB[1], 1, T + 3);
        BAR(); MFMAQ(3); VMC4(); BAR();
    }

    const int r0 = m0 + wr * 128 + lg * 4;
    const int c0 = n0 + wc * 64 + li;
    if (F32OUT) {
        float* C = (float*)Cv;
#pragma unroll
        for (int mi = 0; mi < 8; ++mi)
#pragma unroll
            for (int ni = 0; ni < 4; ++ni)
#pragma unroll
                for (int rr = 0; rr < 4; ++rr)
                    C[(size_t)(r0 + mi * 16 + rr) * N + c0 + ni * 16] = acc[mi][ni][rr];
    } else {
        unsigned short* C = (unsigned short*)Cv;
#pragma unroll
        for (int mi = 0; mi < 8; ++mi)
#pragma unroll
            for (int ni = 0; ni < 4; ++ni)
#pragma unroll
                for (int rr = 0; rr < 4; ++rr)
                    C[(size_t)(r0 + mi * 16 + rr) * N + c0 + ni * 16] = f2bf(acc[mi][ni][rr]);
    }
#undef STG
#undef LDB
#undef LDA
#undef MFMAQ
}

// ================= Flash attention v3: swapped QK^T, register-P, 4-wave blocks =================
// Block: 256 thr (4 waves) = (b, kvh, head-pair): 2 heads x 64 q-rows; 2 blocks/CU (64KB LDS).
// Wave w: head (w>>1), q rows (w&1)*32 .. +32. Paired q-tiles {p, NQT-1-p} -> uniform work.
// Swapped QK: sT = mfma(K,Q) -> lane li owns q-row li; kv = ni*16 + lg*4 + r (in-lane).
// P stays in registers: cvt_pk -> PV A-frag with kv-permutation sigma; V-frags read at sigma
// via 2x ds_read_b64 (same involution swizzle), so both PV operands agree on the kv order.

__device__ __forceinline__ void stage_k_tile4(const unsigned short* kt_base,
                                              unsigned short* ks_base, int w, int lane) {
#pragma unroll
    for (int j = 0; j < 4; ++j) {
        int row = (w * 4 + j) * 4 + (lane >> 4);
        int colb = (lane & 15) * 16;
        int key = (row & 7) << 4;
        gl16(kt_base + (size_t)row * 2048 + ((colb ^ key) >> 1),
             ks_base + (w * 4 + j) * 512);
    }
}

__device__ __forceinline__ void load_v2(const unsigned short* vt_base, int tid, uint4 a[2][2]) {
#pragma unroll
    for (int it = 0; it < 2; ++it) {
        int c = it * 256 + tid;
        int kv = (c >> 4) * 2, d0 = (c & 15) * 8;
        const unsigned short* vp = vt_base + (size_t)kv * 2048 + d0;
        a[it][0] = *(const uint4*)vp;
        a[it][1] = *(const uint4*)(vp + 2048);
    }
}

__device__ __forceinline__ void write_v2(unsigned short* vt_lds, int tid, uint4 a[2][2]) {
#pragma unroll
    for (int it = 0; it < 2; ++it) {
        int c = it * 256 + tid;
        int kv = (c >> 4) * 2, d0 = (c & 15) * 8;
        union { uint4 q; unsigned short u[8]; } x0, x1;
        x0.q = a[it][0]; x1.q = a[it][1];
#pragma unroll
        for (int jj = 0; jj < 8; ++jj) {
            int d = d0 + jj;
            unsigned pack = (unsigned)x0.u[jj] | ((unsigned)x1.u[jj] << 16);
            int key = ((d ^ (d >> 3)) & 7) << 4;
            *(unsigned*)((char*)vt_lds + d * 128 + ((kv * 2) ^ key)) = pack;
        }
    }
}

__global__ void __launch_bounds__(256, 2) attn_kernel(const unsigned short* __restrict__ Q,
                                                      const unsigned short* __restrict__ Kb,
                                                      const unsigned short* __restrict__ Vb,
                                                      unsigned short* __restrict__ O) {
    __shared__ unsigned short Ks[2][64 * 128];   // [kv][d], rows 256B, key=(kv&7)<<4
    __shared__ unsigned short Vt[2][128 * 64];   // [d][kv], rows 128B, key=((d^d>>3)&7)<<4

    const int pidx = blockIdx.x;          // 0..15 pair index
    const int bg = blockIdx.y;            // ((b*8 + kvh)*2 + hp)
    const int b = bg >> 4, kvh = (bg >> 1) & 7, hp = bg & 1;
    const int tid = threadIdx.x;
    const int w = tid >> 6, lane = tid & 63;
    const int li = lane & 15, lg = lane >> 4;
    const int h = kvh * 4 + hp * 2 + (w >> 1);
    const int qh = (w & 1) * 32;

    const unsigned short* KVrow0 = Kb + (size_t)b * S_N * 2048 + kvh * 128;
    const unsigned short* Vrow0  = Vb + (size_t)b * S_N * 2048 + kvh * 128;

#pragma unroll 1
    for (int pass = 0; pass < 2; ++pass) {
        const int qt = pass ? (NQT - 1 - pidx) : pidx;
        const int nt = qt + 1;

        // Q fragments: lane li owns q-row (qt*64 + qh + mi*16 + li)
        bf16x8 qf[2][4];
        {
            const unsigned short* qp = Q + ((size_t)b * S_N + qt * 64 + qh + li) * (H_N * HD_N)
                                         + h * HD_N + lg * 8;
#pragma unroll
            for (int mi = 0; mi < 2; ++mi)
#pragma unroll
                for (int ds = 0; ds < 4; ++ds)
                    qf[mi][ds] = *(const bf16x8*)(qp + (size_t)mi * 16 * (H_N * HD_N) + ds * 32);
        }

        float mreg[2], lreg[2];
#pragma unroll
        for (int mi = 0; mi < 2; ++mi) { mreg[mi] = -1e30f; lreg[mi] = 0.f; }
        f32x4 o_acc[2][8];
#pragma unroll
        for (int mi = 0; mi < 2; ++mi)
#pragma unroll
            for (int di = 0; di < 8; ++di) o_acc[mi][di] = (f32x4){0.f, 0.f, 0.f, 0.f};

        // prologue: stage tile 0 into buf 0
        {
            stage_k_tile4(KVrow0, &Ks[0][0], w, lane);
            uint4 a[2][2];
            load_v2(Vrow0, tid, a);
            write_v2(&Vt[0][0], tid, a);
        }
        __syncthreads();

#pragma unroll 1
        for (int t = 0; t < nt; ++t) {
            const int c = t & 1;
            const bool pre = (t + 1 < nt);
            uint4 a[2][2];
            if (pre) {
                stage_k_tile4(KVrow0 + (size_t)(t + 1) * 64 * 2048, &Ks[c ^ 1][0], w, lane);
                load_v2(Vrow0 + (size_t)(t + 1) * 64 * 2048, tid, a);
            }

            // ---- S^T = K Q^T : lane li owns q-row li; kv = ni*16 + lg*4 + r ----
            f32x4 sT[2][4];
#pragma unroll
            for (int mi = 0; mi < 2; ++mi)
#pragma unroll
                for (int ni = 0; ni < 4; ++ni) sT[mi][ni] = (f32x4){0.f, 0.f, 0.f, 0.f};
#pragma unroll
            for (int ni = 0; ni < 4; ++ni) {
                const int kvc = ni * 16 + li;
                const int kkey = (kvc & 7) << 4;
                bf16x8 kf[4];
#pragma unroll
                for (int ds = 0; ds < 4; ++ds)
                    kf[ds] = *(const bf16x8*)((char*)&Ks[c][0] + kvc * 256
                                              + ((ds * 64 + lg * 16) ^ kkey));
#pragma unroll
                for (int mi = 0; mi < 2; ++mi)
#pragma unroll
                    for (int ds = 0; ds < 4; ++ds)
                        sT[mi][ni] = __builtin_amdgcn_mfma_f32_16x16x32_bf16(kf[ds], qf[mi][ds], sT[mi][ni], 0, 0, 0);
            }

            // ---- causal mask on diagonal tile ----
            if (t == qt) {
#pragma unroll
                for (int mi = 0; mi < 2; ++mi) {
                    int qq = qh + mi * 16 + li;
#pragma unroll
                    for (int ni = 0; ni < 4; ++ni)
#pragma unroll
                        for (int r = 0; r < 4; ++r)
                            if (ni * 16 + lg * 4 + r > qq) sT[mi][ni][r] = -1e30f;
                }
            }

            // ---- online softmax (exp2 domain; row = lane-local) ----
            float fac0[2];
#pragma unroll
            for (int mi = 0; mi < 2; ++mi) {
                float pm = sT[mi][0][0];
#pragma unroll
                for (int ni = 0; ni < 4; ++ni)
#pragma unroll
                    for (int r = 0; r < 4; ++r) pm = fmaxf(pm, sT[mi][ni][r]);
                pm = fmaxf(pm, __shfl_xor(pm, 16));
                pm = fmaxf(pm, __shfl_xor(pm, 32));
                float mn = fmaxf(mreg[mi], pm);
                fac0[mi] = __builtin_amdgcn_exp2f(mreg[mi] - mn);
                mreg[mi] = mn;
#pragma unroll
                for (int ni = 0; ni < 4; ++ni)
#pragma unroll
                    for (int r = 0; r < 4; ++r)
                        sT[mi][ni][r] = __builtin_amdgcn_exp2f(sT[mi][ni][r] - mn);
                float rs = 0.f;
#pragma unroll
                for (int ni = 0; ni < 4; ++ni)
#pragma unroll
                    for (int r = 0; r < 4; ++r) rs += sT[mi][ni][r];
                rs += __shfl_xor(rs, 16);
                rs += __shfl_xor(rs, 32);
                lreg[mi] = lreg[mi] * fac0[mi] + rs;
            }

            // ---- redistribute rescale factor to o_acc row layout (row = lg*4+rr) ----
            float facR[2][4];
#pragma unroll
            for (int mi = 0; mi < 2; ++mi)
#pragma unroll
                for (int rr = 0; rr < 4; ++rr)
                    facR[mi][rr] = __shfl(fac0[mi], (lg << 4) | (lg * 4 + rr));
#pragma unroll
            for (int mi = 0; mi < 2; ++mi)
#pragma unroll
                for (int di = 0; di < 8; ++di)
#pragma unroll
                    for (int rr = 0; rr < 4; ++rr) o_acc[mi][di][rr] *= facR[mi][rr];

            // ---- P -> bf16 A-fragments in registers (kv order sigma: ks*32+16*(j>>2)+lg*4+(j&3)) ----
            union U { bf16x8 v; unsigned u[4]; };
            U pa[2][2];
#pragma unroll
            for (int mi = 0; mi < 2; ++mi)
#pragma unroll
                for (int ks = 0; ks < 2; ++ks) {
                    pa[mi][ks].u[0] = cvt_pk_bf16(sT[mi][2 * ks][0], sT[mi][2 * ks][1]);
                    pa[mi][ks].u[1] = cvt_pk_bf16(sT[mi][2 * ks][2], sT[mi][2 * ks][3]);
                    pa[mi][ks].u[2] = cvt_pk_bf16(sT[mi][2 * ks + 1][0], sT[mi][2 * ks + 1][1]);
                    pa[mi][ks].u[3] = cvt_pk_bf16(sT[mi][2 * ks + 1][2], sT[mi][2 * ks + 1][3]);
                }

            // ---- O += P V  (V-frags read at the same sigma permutation) ----
#pragma unroll
            for (int di = 0; di < 8; ++di) {
                int d = di * 16 + li;
                int vkey = ((d ^ (d >> 3)) & 7) << 4;
                const char* vbase = (const char*)&Vt[c][0] + d * 128;
                bf16x8 vf[2];
#pragma unroll
                for (int ks = 0; ks < 2; ++ks) {
                    union { bf16x8 v; unsigned long long g[2]; } vv;
                    int cb = ks * 64 + lg * 8;
                    vv.g[0] = *(const unsigned long long*)(vbase + (cb ^ vkey));
                    vv.g[1] = *(const unsigned long long*)(vbase + ((cb + 32) ^ vkey));
                    vf[ks] = vv.v;
                }
#pragma unroll
                for (int mi = 0; mi < 2; ++mi)
#pragma unroll
                    for (int ks = 0; ks < 2; ++ks)
                        o_acc[mi][di] = __builtin_amdgcn_mfma_f32_16x16x32_bf16(pa[mi][ks].v, vf[ks], o_acc[mi][di], 0, 0, 0);
            }

            if (pre) write_v2(&Vt[c ^ 1][0], tid, a);
            __syncthreads();
        }

        // ---- epilogue: divide by row sums (redistribute inv to row layout), write O ----
        unsigned short* op = O + ((size_t)b * S_N + qt * 64 + qh + lg * 4) * (H_N * HD_N)
                               + h * HD_N + li;
#pragma unroll
        for (int mi = 0; mi < 2; ++mi) {
            float iv = 1.f / lreg[mi];
            float ivR[4];
#pragma unroll
            for (int rr = 0; rr < 4; ++rr)
                ivR[rr] = __shfl(iv, (lg << 4) | (lg * 4 + rr));
#pragma unroll
            for (int di = 0; di < 8; ++di)
#pragma unroll
                for (int rr = 0; rr < 4; ++rr)
                    op[((size_t)(mi * 16 + rr)) * (H_N * HD_N) + di * 16]
                        = f2bf(o_acc[mi][di][rr] * ivR[rr]);
        }
    }
}

// ---------------- launch ----------------
extern "C" void kernel_launch(void* const* d_in, const int* in_sizes, int n_in,
                              void* d_out, int out_size, void* d_ws, size_t ws_size,
                              hipStream_t stream) {
    (void)in_sizes; (void)n_in; (void)out_size; (void)ws_size;
    const float* x  = (const float*)d_in[0];
    const float* wq = (const float*)d_in[1];
    const float* wk = (const float*)d_in[2];
    const float* wv = (const float*)d_in[3];
    const float* wo = (const float*)d_in[4];
    const float* fc = (const float*)d_in[5];
    const float* fs = (const float*)d_in[6];
    float* out = (float*)d_out;

    char* ws = (char*)d_ws;
    unsigned short* xb  = (unsigned short*)(ws);                // 33.5MB  x bf16
    unsigned short* wb  = (unsigned short*)(ws + 33554432);     // 33.5MB  wq, later wo
    unsigned short* wkv = (unsigned short*)(ws + 67108864);     // 16.8MB  [wk;wv]
    unsigned short* Qb  = (unsigned short*)(ws + 83886080);     // 33.5MB  Q, later attn-O
    unsigned short* KVb = (unsigned short*)(ws + 117440512);    // 16.8MB  [K|V] rows of 2048

    const int BS = B_N * S_N;  // 4096

    conv_f32_bf16<<<dim3(BS * D_N / 1024), 256, 0, stream>>>(x, xb);
    conv_f32_bf16<<<dim3(H_N * HD_N * D_N / 1024), 256, 0, stream>>>(wq, wb);
    conv_f32_bf16<<<dim3(KVH_N * HD_N * D_N / 1024), 256, 0, stream>>>(wk, wkv);
    conv_f32_bf16<<<dim3(KVH_N * HD_N * D_N / 1024), 256, 0, stream>>>(wv, wkv + KVH_N * HD_N * D_N);

    // Q = x wq^T  (bf16 out), 256^2 8-phase
    gemm256<0><<<dim3((BS / 256) * (D_N / 256)), 512, 0, stream>>>(xb, wb, Qb, BS, D_N, D_N);
    conv_f32_bf16<<<dim3(D_N * H_N * HD_N / 1024), 256, 0, stream>>>(wo, wb);
    // [K|V] = x [wk;wv]^T
    gemm256<0><<<dim3((BS / 256) * (2048 / 256)), 512, 0, stream>>>(xb, wkv, KVb, BS, 2048, D_N);

    // RoPE: Q (scale = 1/sqrt(HD) * log2e folded; softmax in exp2 domain), K plain
    rope_kernel<H_N, H_N * HD_N><<<dim3(BS * H_N * 64 / 256), 256, 0, stream>>>(Qb, fc, fs, QS_LOG2E);
    rope_kernel<KVH_N, 2 * KVH_N * HD_N><<<dim3(BS * KVH_N * 64 / 256), 256, 0, stream>>>(KVb, fc, fs, 1.0f);

    // attention: 512 blocks (2/CU), 4 waves each; writes O in-place over Qb
    attn_kernel<<<dim3(NQT / 2, B_N * KVH_N * 2), 256, 0, stream>>>(Qb, KVb, KVb + 1024, Qb);

    // out = O wo^T (f32 out)
    gemm256<1><<<dim3((BS / 256) * (D_N / 256)), 512, 0, stream>>>(Qb, wb, out, BS, D_N, D_N);
}